// Round 2
// baseline (73.419 us; speedup 1.0000x reference)
//
#include <hip/hip_runtime.h>
#include <cmath>

namespace {

typedef float f32x4 __attribute__((ext_vector_type(4)));

constexpr int Bb   = 128;
constexpr int Nn   = 32;
constexpr int Tt   = 50;
constexpr int Hh   = 128;
constexpr int HOPS = 8;
constexpr int NT   = Nn * Tt;                  // 1600
constexpr int POS_PER_BLOCK = 64;
constexpr int CHUNKS = NT / POS_PER_BLOCK;     // 25

// Kernel A: s1[b][nt][a] = (sum_h neigh[b,nt,h]*node[b,t,h]*W[a,h] + bias[a]) / sqrt(nn[0])
// written into the BA slot (temporary [b][nt][a] layout), plus neigh -> neigh_r copy.
__global__ __launch_bounds__(256) void ga_s1_copy(
    const float* __restrict__ node,     // [B][T][H]
    const float* __restrict__ neigh,    // [B][NT][H]
    const int*   __restrict__ nn,       // [B]
    const float* __restrict__ W,        // [HOPS][H]
    const float* __restrict__ bias,     // [HOPS]
    float* __restrict__ s1g,            // [B][NT][HOPS]  (aliases BA output slot)
    float* __restrict__ neigh_r)        // [B][NT][H]
{
    const int lane16 = threadIdx.x & 15;   // h-slice owner within a 16-lane group
    const int group  = threadIdx.x >> 4;   // 16 position-groups per block
    const int chunk  = blockIdx.x % CHUNKS;
    const int b      = blockIdx.x / CHUNKS;

    const float rscale = rsqrtf((float)nn[0]);

    // W fragment for this thread's fixed h-slice (h = lane16*8 .. +7)
    f32x4 w0[HOPS], w1[HOPS];
    #pragma unroll
    for (int a = 0; a < HOPS; ++a) {
        const f32x4* wp = reinterpret_cast<const f32x4*>(W + a * Hh + lane16 * 8);
        w0[a] = wp[0];
        w1[a] = wp[1];
    }
    const float bl = bias[lane16 >> 1];   // hop owned by this lane-pair after butterfly

    const int pos0 = chunk * POS_PER_BLOCK + group;       // pass p handles pos0 + 16p
    const size_t base = ((size_t)b * NT + pos0) * Hh + lane16 * 8;

    // 1) hoist all 4 passes' neigh loads: 8 dwordx4 in flight
    f32x4 nb[4][2];
    #pragma unroll
    for (int p = 0; p < 4; ++p) {
        const f32x4* np = reinterpret_cast<const f32x4*>(neigh + base + (size_t)p * 16 * Hh);
        nb[p][0] = __builtin_nontemporal_load(np);
        nb[p][1] = __builtin_nontemporal_load(np + 1);
    }
    // 2) fused passthrough copy (exact f32), streaming stores
    #pragma unroll
    for (int p = 0; p < 4; ++p) {
        f32x4* cp = reinterpret_cast<f32x4*>(neigh_r + base + (size_t)p * 16 * Hh);
        __builtin_nontemporal_store(nb[p][0], cp);
        __builtin_nontemporal_store(nb[p][1], cp + 1);
    }

    // 3) compute + payload-split butterfly reduce (8 shuffles per pass)
    #pragma unroll
    for (int p = 0; p < 4; ++p) {
        const int pos = pos0 + p * 16;
        const int t   = pos % Tt;
        const f32x4* dp = reinterpret_cast<const f32x4*>(node + ((size_t)b * Tt + t) * Hh + lane16 * 8);
        const f32x4 pr0 = nb[p][0] * dp[0];
        const f32x4 pr1 = nb[p][1] * dp[1];

        float acc[HOPS];
        #pragma unroll
        for (int a = 0; a < HOPS; ++a) {
            acc[a] = pr0[0] * w0[a][0] + pr0[1] * w0[a][1] + pr0[2] * w0[a][2] + pr0[3] * w0[a][3]
                   + pr1[0] * w1[a][0] + pr1[1] * w1[a][1] + pr1[2] * w1[a][2] + pr1[3] * w1[a][3];
        }

        // Level 1 (xor 8): keep own half of hop-set, exchange the other half.
        const bool h8 = (lane16 & 8) != 0;
        float r[4];
        #pragma unroll
        for (int k = 0; k < 4; ++k) {
            float send = h8 ? acc[k] : acc[k + 4];
            r[k] = (h8 ? acc[k + 4] : acc[k]) + __shfl_xor(send, 8, 64);
        }
        // Level 2 (xor 4)
        const bool h4 = (lane16 & 4) != 0;
        float s2[2];
        #pragma unroll
        for (int k = 0; k < 2; ++k) {
            float send = h4 ? r[k] : r[k + 2];
            s2[k] = (h4 ? r[k + 2] : r[k]) + __shfl_xor(send, 4, 64);
        }
        // Level 3 (xor 2)
        const bool h2 = (lane16 & 2) != 0;
        float send3 = h2 ? s2[0] : s2[1];
        float u = (h2 ? s2[1] : s2[0]) + __shfl_xor(send3, 2, 64);
        // Level 4 (xor 1): full sum; lane 2k (and 2k+1) now hold hop k's total
        u += __shfl_xor(u, 1, 64);

        if (!(lane16 & 1)) {
            s1g[((size_t)b * NT + pos) * HOPS + (lane16 >> 1)] = (u + bl) * rscale;
        }
    }
}

// Kernel B: per-b softmax over NT per hop; rewrites BA slot [b][nt][a] -> [b][a][nt]
// (softmaxed) in place (all source values staged in LDS first), and BW = sum_a BA.
__global__ __launch_bounds__(256) void ga_softmax(float* __restrict__ out)
{
    float* BW = out;                       // [B][NT]
    float* BA = out + Bb * NT;             // [B][HOPS][NT]; currently holds s1 [B][NT][HOPS]
    const int b   = blockIdx.x;
    const int tid = threadIdx.x;

    __shared__ float s[NT * 9];            // +1 pad per row: stride 9, conflict-free columns
    __shared__ float sm_m[HOPS], sm_inv[HOPS];

    const float* src = BA + (size_t)b * NT * HOPS;
    for (int idx = tid; idx < NT * HOPS; idx += 256) {
        const int nt = idx >> 3;
        const int a  = idx & 7;
        s[nt * 9 + a] = src[idx];
    }
    __syncthreads();

    const int w    = tid >> 6;   // wave 0..3 -> hops {2w, 2w+1}
    const int lane = tid & 63;
    #pragma unroll
    for (int rep = 0; rep < 2; ++rep) {
        const int a = w * 2 + rep;
        float m = -INFINITY;
        for (int nt = lane; nt < NT; nt += 64) m = fmaxf(m, s[nt * 9 + a]);
        #pragma unroll
        for (int off = 32; off >= 1; off >>= 1) m = fmaxf(m, __shfl_xor(m, off, 64));
        float sum = 0.f;
        for (int nt = lane; nt < NT; nt += 64) sum += __expf(s[nt * 9 + a] - m);
        #pragma unroll
        for (int off = 32; off >= 1; off >>= 1) sum += __shfl_xor(sum, off, 64);
        if (lane == 0) { sm_m[a] = m; sm_inv[a] = 1.0f / sum; }
    }
    __syncthreads();

    float bw[7] = {0.f, 0.f, 0.f, 0.f, 0.f, 0.f, 0.f};
    float* bab = BA + (size_t)b * HOPS * NT;
    #pragma unroll
    for (int a = 0; a < HOPS; ++a) {
        const float m   = sm_m[a];
        const float inv = sm_inv[a];
        #pragma unroll
        for (int k = 0; k < 7; ++k) {
            const int nt = tid + k * 256;
            if (nt < NT) {
                const float v = __expf(s[nt * 9 + a] - m) * inv;
                bab[a * NT + nt] = v;   // coalesced per hop-plane
                bw[k] += v;
            }
        }
    }
    float* bwb = BW + (size_t)b * NT;
    #pragma unroll
    for (int k = 0; k < 7; ++k) {
        const int nt = tid + k * 256;
        if (nt < NT) bwb[nt] = bw[k];
    }
}

} // namespace

extern "C" void kernel_launch(void* const* d_in, const int* in_sizes, int n_in,
                              void* d_out, int out_size, void* d_ws, size_t ws_size,
                              hipStream_t stream) {
    const float* node  = (const float*)d_in[0];   // [128][50][128] f32
    const float* neigh = (const float*)d_in[1];   // [128][32][50][128] f32
    const int*   nn    = (const int*)d_in[2];     // [128] i32
    const float* W     = (const float*)d_in[3];   // [8][128] f32
    const float* bias  = (const float*)d_in[4];   // [8] f32

    float* out     = (float*)d_out;
    float* BA      = out + Bb * NT;            // after BW (204800)
    float* neigh_r = BA + Bb * HOPS * NT;      // after BA (1638400)

    ga_s1_copy<<<dim3(Bb * CHUNKS), dim3(256), 0, stream>>>(node, neigh, nn, W, bias, BA, neigh_r);
    ga_softmax<<<dim3(Bb), dim3(256), 0, stream>>>(out);
}

// Round 3
// 55.434 us; speedup vs baseline: 1.3245x; 1.3245x over previous
//
#include <hip/hip_runtime.h>
#include <cmath>

namespace {

typedef float f32x4 __attribute__((ext_vector_type(4)));

constexpr int Bb   = 128;
constexpr int Nn   = 32;
constexpr int Tt   = 50;
constexpr int Hh   = 128;
constexpr int HOPS = 8;
constexpr int NT   = Nn * Tt;                  // 1600
constexpr int POS_PER_BLOCK = 64;
constexpr int CHUNKS = NT / POS_PER_BLOCK;     // 25

// Kernel A: s1[b][nt][a] = (sum_h neigh[b,nt,h]*node[b,t,h]*W[a,h] + bias[a]) / sqrt(nn[0])
// written into the BA slot (temporary [b][nt][a] layout), plus neigh -> neigh_r copy.
__global__ __launch_bounds__(256) void ga_s1_copy(
    const float* __restrict__ node,     // [B][T][H]
    const float* __restrict__ neigh,    // [B][NT][H]
    const int*   __restrict__ nn,       // [B]
    const float* __restrict__ W,        // [HOPS][H]
    const float* __restrict__ bias,     // [HOPS]
    float* __restrict__ s1g,            // [B][NT][HOPS]  (aliases BA output slot)
    float* __restrict__ neigh_r)        // [B][NT][H]
{
    const int lane16 = threadIdx.x & 15;   // h-slice owner within a 16-lane group
    const int group  = threadIdx.x >> 4;   // 16 position-groups per block
    const int chunk  = blockIdx.x % CHUNKS;
    const int b      = blockIdx.x / CHUNKS;

    const float rscale = rsqrtf((float)nn[0]);

    // W fragment for this thread's fixed h-slice (h = lane16*8 .. +7)
    f32x4 w0[HOPS], w1[HOPS];
    #pragma unroll
    for (int a = 0; a < HOPS; ++a) {
        const f32x4* wp = reinterpret_cast<const f32x4*>(W + a * Hh + lane16 * 8);
        w0[a] = wp[0];
        w1[a] = wp[1];
    }
    const float bl = bias[lane16 >> 1];   // hop owned by this lane-pair after butterfly

    const int pos0 = chunk * POS_PER_BLOCK + group;       // pass p handles pos0 + 16p
    const size_t base = ((size_t)b * NT + pos0) * Hh + lane16 * 8;

    // 1) hoist all 4 passes' neigh loads: 8 dwordx4 in flight (temporal — L3 reuse
    //    across graph replays matters; nt hints regressed R2 by 17 us)
    f32x4 nb[4][2];
    #pragma unroll
    for (int p = 0; p < 4; ++p) {
        const f32x4* np = reinterpret_cast<const f32x4*>(neigh + base + (size_t)p * 16 * Hh);
        nb[p][0] = np[0];
        nb[p][1] = np[1];
    }
    // 2) fused passthrough copy (exact f32)
    #pragma unroll
    for (int p = 0; p < 4; ++p) {
        f32x4* cp = reinterpret_cast<f32x4*>(neigh_r + base + (size_t)p * 16 * Hh);
        cp[0] = nb[p][0];
        cp[1] = nb[p][1];
    }

    // 3) compute + payload-split butterfly reduce (8 shuffles per pass)
    #pragma unroll
    for (int p = 0; p < 4; ++p) {
        const int pos = pos0 + p * 16;
        const int t   = pos % Tt;
        const f32x4* dp = reinterpret_cast<const f32x4*>(node + ((size_t)b * Tt + t) * Hh + lane16 * 8);
        const f32x4 pr0 = nb[p][0] * dp[0];
        const f32x4 pr1 = nb[p][1] * dp[1];

        float acc[HOPS];
        #pragma unroll
        for (int a = 0; a < HOPS; ++a) {
            acc[a] = pr0[0] * w0[a][0] + pr0[1] * w0[a][1] + pr0[2] * w0[a][2] + pr0[3] * w0[a][3]
                   + pr1[0] * w1[a][0] + pr1[1] * w1[a][1] + pr1[2] * w1[a][2] + pr1[3] * w1[a][3];
        }

        // Level 1 (xor 8): keep own half of hop-set, exchange the other half.
        const bool h8 = (lane16 & 8) != 0;
        float r[4];
        #pragma unroll
        for (int k = 0; k < 4; ++k) {
            float send = h8 ? acc[k] : acc[k + 4];
            r[k] = (h8 ? acc[k + 4] : acc[k]) + __shfl_xor(send, 8, 64);
        }
        // Level 2 (xor 4)
        const bool h4 = (lane16 & 4) != 0;
        float s2[2];
        #pragma unroll
        for (int k = 0; k < 2; ++k) {
            float send = h4 ? r[k] : r[k + 2];
            s2[k] = (h4 ? r[k + 2] : r[k]) + __shfl_xor(send, 4, 64);
        }
        // Level 3 (xor 2)
        const bool h2 = (lane16 & 2) != 0;
        float send3 = h2 ? s2[0] : s2[1];
        float u = (h2 ? s2[1] : s2[0]) + __shfl_xor(send3, 2, 64);
        // Level 4 (xor 1): full sum; lane 2k (and 2k+1) now hold hop k's total
        u += __shfl_xor(u, 1, 64);

        if (!(lane16 & 1)) {
            s1g[((size_t)b * NT + pos) * HOPS + (lane16 >> 1)] = (u + bl) * rscale;
        }
    }
}

// Kernel B: per-b softmax over NT per hop; rewrites BA slot [b][nt][a] -> [b][a][nt]
// (softmaxed) in place (all source values staged in LDS first), and BW = sum_a BA.
__global__ __launch_bounds__(256) void ga_softmax(float* __restrict__ out)
{
    float* BW = out;                       // [B][NT]
    float* BA = out + Bb * NT;             // [B][HOPS][NT]; currently holds s1 [B][NT][HOPS]
    const int b   = blockIdx.x;
    const int tid = threadIdx.x;

    __shared__ float s[NT * 9];            // +1 pad per row: stride 9, conflict-free columns
    __shared__ float sm_m[HOPS], sm_inv[HOPS];

    const float* src = BA + (size_t)b * NT * HOPS;
    for (int idx = tid; idx < NT * HOPS; idx += 256) {
        const int nt = idx >> 3;
        const int a  = idx & 7;
        s[nt * 9 + a] = src[idx];
    }
    __syncthreads();

    const int w    = tid >> 6;   // wave 0..3 -> hops {2w, 2w+1}
    const int lane = tid & 63;
    #pragma unroll
    for (int rep = 0; rep < 2; ++rep) {
        const int a = w * 2 + rep;
        float m = -INFINITY;
        for (int nt = lane; nt < NT; nt += 64) m = fmaxf(m, s[nt * 9 + a]);
        #pragma unroll
        for (int off = 32; off >= 1; off >>= 1) m = fmaxf(m, __shfl_xor(m, off, 64));
        float sum = 0.f;
        for (int nt = lane; nt < NT; nt += 64) sum += __expf(s[nt * 9 + a] - m);
        #pragma unroll
        for (int off = 32; off >= 1; off >>= 1) sum += __shfl_xor(sum, off, 64);
        if (lane == 0) { sm_m[a] = m; sm_inv[a] = 1.0f / sum; }
    }
    __syncthreads();

    float bw[7] = {0.f, 0.f, 0.f, 0.f, 0.f, 0.f, 0.f};
    float* bab = BA + (size_t)b * HOPS * NT;
    #pragma unroll
    for (int a = 0; a < HOPS; ++a) {
        const float m   = sm_m[a];
        const float inv = sm_inv[a];
        #pragma unroll
        for (int k = 0; k < 7; ++k) {
            const int nt = tid + k * 256;
            if (nt < NT) {
                const float v = __expf(s[nt * 9 + a] - m) * inv;
                bab[a * NT + nt] = v;   // coalesced per hop-plane
                bw[k] += v;
            }
        }
    }
    float* bwb = BW + (size_t)b * NT;
    #pragma unroll
    for (int k = 0; k < 7; ++k) {
        const int nt = tid + k * 256;
        if (nt < NT) bwb[nt] = bw[k];
    }
}

} // namespace

extern "C" void kernel_launch(void* const* d_in, const int* in_sizes, int n_in,
                              void* d_out, int out_size, void* d_ws, size_t ws_size,
                              hipStream_t stream) {
    const float* node  = (const float*)d_in[0];   // [128][50][128] f32
    const float* neigh = (const float*)d_in[1];   // [128][32][50][128] f32
    const int*   nn    = (const int*)d_in[2];     // [128] i32
    const float* W     = (const float*)d_in[3];   // [8][128] f32
    const float* bias  = (const float*)d_in[4];   // [8] f32

    float* out     = (float*)d_out;
    float* BA      = out + Bb * NT;            // after BW (204800)
    float* neigh_r = BA + Bb * HOPS * NT;      // after BA (1638400)

    ga_s1_copy<<<dim3(Bb * CHUNKS), dim3(256), 0, stream>>>(node, neigh, nn, W, bias, BA, neigh_r);
    ga_softmax<<<dim3(Bb), dim3(256), 0, stream>>>(out);
}

// Round 4
// 52.595 us; speedup vs baseline: 1.3959x; 1.0540x over previous
//
#include <hip/hip_runtime.h>
#include <cmath>

namespace {

typedef float f32x4 __attribute__((ext_vector_type(4)));

constexpr int Bb   = 128;
constexpr int Nn   = 32;
constexpr int Tt   = 50;
constexpr int Hh   = 128;
constexpr int HOPS = 8;
constexpr int NT   = Nn * Tt;                  // 1600
constexpr int PPT  = 5;                        // positions per thread (passes)
constexpr int POS_PER_BLOCK = 16 * PPT;        // 80
constexpr int CHUNKS = NT / POS_PER_BLOCK;     // 20

// Kernel A: s1T[b][a][nt] = (sum_h neigh[b,nt,h]*node[b,t,h]*W[a,h] + b[a]) * rsqrt(nn[0])
// stored directly in the FINAL BA layout (softmax then rewrites rows in place),
// plus neigh -> neigh_r passthrough copy.
__global__ __launch_bounds__(256) void ga_s1_copy(
    const float* __restrict__ node,     // [B][T][H]
    const float* __restrict__ neigh,    // [B][NT][H]
    const int*   __restrict__ nn,       // [B]
    const float* __restrict__ W,        // [HOPS][H]
    const float* __restrict__ bias,     // [HOPS]
    float* __restrict__ s1T,            // [B][HOPS][NT]  (aliases BA output slot)
    float* __restrict__ neigh_r)        // [B][NT][H]
{
    const int lane16 = threadIdx.x & 15;   // h-slice owner within a 16-lane group
    const int group  = threadIdx.x >> 4;   // 16 position-groups per block
    const int chunk  = blockIdx.x % CHUNKS;
    const int b      = blockIdx.x / CHUNKS;

    const float rscale = rsqrtf((float)nn[0]);

    // W fragment for this thread's fixed h-slice (h = lane16*8 .. +7)
    f32x4 w0[HOPS], w1[HOPS];
    #pragma unroll
    for (int a = 0; a < HOPS; ++a) {
        const f32x4* wp = reinterpret_cast<const f32x4*>(W + a * Hh + lane16 * 8);
        w0[a] = wp[0];
        w1[a] = wp[1];
    }
    const float bl = bias[lane16 >> 1];   // hop owned by this lane-pair after butterfly

    const int pos0 = chunk * POS_PER_BLOCK + group;       // pass p handles pos0 + 16p
    const size_t base = ((size_t)b * NT + pos0) * Hh + lane16 * 8;

    // 1) hoist all passes' neigh loads: 2*PPT dwordx4 in flight (temporal — L3 reuse
    //    across graph replays matters; nt hints regressed R2 by 17 us)
    f32x4 nb[PPT][2];
    #pragma unroll
    for (int p = 0; p < PPT; ++p) {
        const f32x4* np = reinterpret_cast<const f32x4*>(neigh + base + (size_t)p * 16 * Hh);
        nb[p][0] = np[0];
        nb[p][1] = np[1];
    }
    // 2) fused passthrough copy (exact f32)
    #pragma unroll
    for (int p = 0; p < PPT; ++p) {
        f32x4* cp = reinterpret_cast<f32x4*>(neigh_r + base + (size_t)p * 16 * Hh);
        cp[0] = nb[p][0];
        cp[1] = nb[p][1];
    }

    // 3) compute + payload-split butterfly reduce (8 shuffles per pass)
    #pragma unroll
    for (int p = 0; p < PPT; ++p) {
        const int pos = pos0 + p * 16;
        const int t   = pos % Tt;
        const f32x4* dp = reinterpret_cast<const f32x4*>(node + ((size_t)b * Tt + t) * Hh + lane16 * 8);
        const f32x4 pr0 = nb[p][0] * dp[0];
        const f32x4 pr1 = nb[p][1] * dp[1];

        float acc[HOPS];
        #pragma unroll
        for (int a = 0; a < HOPS; ++a) {
            acc[a] = pr0[0] * w0[a][0] + pr0[1] * w0[a][1] + pr0[2] * w0[a][2] + pr0[3] * w0[a][3]
                   + pr1[0] * w1[a][0] + pr1[1] * w1[a][1] + pr1[2] * w1[a][2] + pr1[3] * w1[a][3];
        }

        // Level 1 (xor 8): keep own half of hop-set, exchange the other half.
        const bool h8 = (lane16 & 8) != 0;
        float r[4];
        #pragma unroll
        for (int k = 0; k < 4; ++k) {
            float send = h8 ? acc[k] : acc[k + 4];
            r[k] = (h8 ? acc[k + 4] : acc[k]) + __shfl_xor(send, 8, 64);
        }
        // Level 2 (xor 4)
        const bool h4 = (lane16 & 4) != 0;
        float s2[2];
        #pragma unroll
        for (int k = 0; k < 2; ++k) {
            float send = h4 ? r[k] : r[k + 2];
            s2[k] = (h4 ? r[k + 2] : r[k]) + __shfl_xor(send, 4, 64);
        }
        // Level 3 (xor 2)
        const bool h2 = (lane16 & 2) != 0;
        float send3 = h2 ? s2[0] : s2[1];
        float u = (h2 ? s2[1] : s2[0]) + __shfl_xor(send3, 2, 64);
        // Level 4 (xor 1): full sum; lane 2k (and 2k+1) now hold hop k's total
        u += __shfl_xor(u, 1, 64);

        if (!(lane16 & 1)) {
            const int k = lane16 >> 1;
            s1T[((size_t)b * HOPS + k) * NT + pos] = (u + bl) * rscale;
        }
    }
}

// Kernel B: one block per (b, a) row. Register-resident softmax over NT=1600,
// in-place rewrite of the row.
__global__ __launch_bounds__(256) void ga_softmax_rows(float* __restrict__ BA)
{
    const int a = blockIdx.x & 7;
    const int b = blockIdx.x >> 3;
    float* row = BA + ((size_t)b * HOPS + a) * NT;

    const int tid  = threadIdx.x;
    const int wv   = tid >> 6;
    const int lane = tid & 63;

    float v[7];
    #pragma unroll
    for (int k = 0; k < 7; ++k) {
        const int nt = tid + k * 256;
        v[k] = (nt < NT) ? row[nt] : -INFINITY;
    }

    __shared__ float red[4];

    // block max
    float m = v[0];
    #pragma unroll
    for (int k = 1; k < 7; ++k) m = fmaxf(m, v[k]);
    #pragma unroll
    for (int off = 32; off >= 1; off >>= 1) m = fmaxf(m, __shfl_xor(m, off, 64));
    if (lane == 0) red[wv] = m;
    __syncthreads();
    m = fmaxf(fmaxf(red[0], red[1]), fmaxf(red[2], red[3]));
    __syncthreads();

    // exp + block sum
    float e[7];
    float s = 0.f;
    #pragma unroll
    for (int k = 0; k < 7; ++k) {
        const int nt = tid + k * 256;
        e[k] = (nt < NT) ? __expf(v[k] - m) : 0.f;
        s += e[k];
    }
    #pragma unroll
    for (int off = 32; off >= 1; off >>= 1) s += __shfl_xor(s, off, 64);
    if (lane == 0) red[wv] = s;
    __syncthreads();
    const float inv = 1.0f / (red[0] + red[1] + red[2] + red[3]);

    #pragma unroll
    for (int k = 0; k < 7; ++k) {
        const int nt = tid + k * 256;
        if (nt < NT) row[nt] = e[k] * inv;
    }
}

// Kernel C: BW[b][nt] = sum_a BA[b][a][nt]
__global__ __launch_bounds__(256) void ga_bw(const float* __restrict__ BA,
                                             float* __restrict__ BW)
{
    const int b  = blockIdx.y;
    const int nt = blockIdx.x * 256 + threadIdx.x;
    if (nt >= NT) return;
    const float* base = BA + (size_t)b * HOPS * NT + nt;
    float s = 0.f;
    #pragma unroll
    for (int a = 0; a < HOPS; ++a) s += base[a * NT];
    BW[(size_t)b * NT + nt] = s;
}

} // namespace

extern "C" void kernel_launch(void* const* d_in, const int* in_sizes, int n_in,
                              void* d_out, int out_size, void* d_ws, size_t ws_size,
                              hipStream_t stream) {
    const float* node  = (const float*)d_in[0];   // [128][50][128] f32
    const float* neigh = (const float*)d_in[1];   // [128][32][50][128] f32
    const int*   nn    = (const int*)d_in[2];     // [128] i32
    const float* W     = (const float*)d_in[3];   // [8][128] f32
    const float* bias  = (const float*)d_in[4];   // [8] f32

    float* out     = (float*)d_out;
    float* BA      = out + Bb * NT;            // after BW (204800)
    float* neigh_r = BA + Bb * HOPS * NT;      // after BA (1638400)

    ga_s1_copy<<<dim3(Bb * CHUNKS), dim3(256), 0, stream>>>(node, neigh, nn, W, bias, BA, neigh_r);
    ga_softmax_rows<<<dim3(Bb * HOPS), dim3(256), 0, stream>>>(BA);
    ga_bw<<<dim3((NT + 255) / 256, Bb), dim3(256), 0, stream>>>(BA, out);
}

// Round 5
// 50.795 us; speedup vs baseline: 1.4454x; 1.0354x over previous
//
#include <hip/hip_runtime.h>
#include <cmath>

namespace {

typedef float f32x4 __attribute__((ext_vector_type(4)));

constexpr int Bb   = 128;
constexpr int Nn   = 32;
constexpr int Tt   = 50;
constexpr int Hh   = 128;
constexpr int HOPS = 8;
constexpr int NT   = Nn * Tt;                  // 1600
constexpr int PPT  = 5;                        // positions per thread (passes)
constexpr int POS_PER_BLOCK = 16 * PPT;        // 80
constexpr int CHUNKS = NT / POS_PER_BLOCK;     // 20

// Kernel A: s1T[b][a][nt] = (sum_h neigh[b,nt,h]*node[b,t,h]*W[a,h] + b[a]) * rsqrt(nn[0])
// stored directly in the FINAL BA layout (softmax then rewrites rows in place),
// plus neigh -> neigh_r passthrough copy.
__global__ __launch_bounds__(256) void ga_s1_copy(
    const float* __restrict__ node,     // [B][T][H]
    const float* __restrict__ neigh,    // [B][NT][H]
    const int*   __restrict__ nn,       // [B]
    const float* __restrict__ W,        // [HOPS][H]
    const float* __restrict__ bias,     // [HOPS]
    float* __restrict__ s1T,            // [B][HOPS][NT]  (aliases BA output slot)
    float* __restrict__ neigh_r)        // [B][NT][H]
{
    const int lane16 = threadIdx.x & 15;   // h-slice owner within a 16-lane group
    const int group  = threadIdx.x >> 4;   // 16 position-groups per block
    const int chunk  = blockIdx.x % CHUNKS;
    const int b      = blockIdx.x / CHUNKS;

    const float rscale = rsqrtf((float)nn[0]);

    // W fragment for this thread's fixed h-slice (h = lane16*8 .. +7)
    f32x4 w0[HOPS], w1[HOPS];
    #pragma unroll
    for (int a = 0; a < HOPS; ++a) {
        const f32x4* wp = reinterpret_cast<const f32x4*>(W + a * Hh + lane16 * 8);
        w0[a] = wp[0];
        w1[a] = wp[1];
    }
    const float bl = bias[lane16 >> 1];   // hop owned by this lane-pair after butterfly

    const int pos0 = chunk * POS_PER_BLOCK + group;       // pass p handles pos0 + 16p
    const size_t base = ((size_t)b * NT + pos0) * Hh + lane16 * 8;

    // 1) hoist all passes' neigh loads: 2*PPT dwordx4 in flight (temporal — L3 reuse
    //    across graph replays matters; nt hints regressed R2 by 17 us)
    f32x4 nb[PPT][2];
    #pragma unroll
    for (int p = 0; p < PPT; ++p) {
        const f32x4* np = reinterpret_cast<const f32x4*>(neigh + base + (size_t)p * 16 * Hh);
        nb[p][0] = np[0];
        nb[p][1] = np[1];
    }
    // 2) fused passthrough copy (exact f32)
    #pragma unroll
    for (int p = 0; p < PPT; ++p) {
        f32x4* cp = reinterpret_cast<f32x4*>(neigh_r + base + (size_t)p * 16 * Hh);
        cp[0] = nb[p][0];
        cp[1] = nb[p][1];
    }

    // 3) compute + payload-split butterfly reduce (8 shuffles per pass)
    #pragma unroll
    for (int p = 0; p < PPT; ++p) {
        const int pos = pos0 + p * 16;
        const int t   = pos % Tt;
        const f32x4* dp = reinterpret_cast<const f32x4*>(node + ((size_t)b * Tt + t) * Hh + lane16 * 8);
        const f32x4 pr0 = nb[p][0] * dp[0];
        const f32x4 pr1 = nb[p][1] * dp[1];

        float acc[HOPS];
        #pragma unroll
        for (int a = 0; a < HOPS; ++a) {
            acc[a] = pr0[0] * w0[a][0] + pr0[1] * w0[a][1] + pr0[2] * w0[a][2] + pr0[3] * w0[a][3]
                   + pr1[0] * w1[a][0] + pr1[1] * w1[a][1] + pr1[2] * w1[a][2] + pr1[3] * w1[a][3];
        }

        // Level 1 (xor 8): keep own half of hop-set, exchange the other half.
        const bool h8 = (lane16 & 8) != 0;
        float r[4];
        #pragma unroll
        for (int k = 0; k < 4; ++k) {
            float send = h8 ? acc[k] : acc[k + 4];
            r[k] = (h8 ? acc[k + 4] : acc[k]) + __shfl_xor(send, 8, 64);
        }
        // Level 2 (xor 4)
        const bool h4 = (lane16 & 4) != 0;
        float s2[2];
        #pragma unroll
        for (int k = 0; k < 2; ++k) {
            float send = h4 ? r[k] : r[k + 2];
            s2[k] = (h4 ? r[k + 2] : r[k]) + __shfl_xor(send, 4, 64);
        }
        // Level 3 (xor 2)
        const bool h2 = (lane16 & 2) != 0;
        float send3 = h2 ? s2[0] : s2[1];
        float u = (h2 ? s2[1] : s2[0]) + __shfl_xor(send3, 2, 64);
        // Level 4 (xor 1): full sum; lane 2k (and 2k+1) now hold hop k's total
        u += __shfl_xor(u, 1, 64);

        if (!(lane16 & 1)) {
            const int k = lane16 >> 1;
            s1T[((size_t)b * HOPS + k) * NT + pos] = (u + bl) * rscale;
        }
    }
}

// Kernel D (fused B+C): one block per b. 1024 threads = 8 hop-rows x 128 threads.
// Register-resident softmax per row, P staged in padded LDS tile, BW summed in-block.
__global__ __launch_bounds__(1024) void ga_softmax_bw(float* __restrict__ out)
{
    float* BW = out;                       // [B][NT]
    float* BA = out + Bb * NT;             // [B][HOPS][NT] (holds s1T; rewritten in place)
    const int b  = blockIdx.x;
    const int tl = threadIdx.x & 127;      // position lane within the row
    const int r  = threadIdx.x >> 7;       // hop-row 0..7 (waves 2r, 2r+1)
    const int wave = threadIdx.x >> 6;
    const int lane = threadIdx.x & 63;

    float* row = BA + ((size_t)b * HOPS + r) * NT;

    // 13 strided values per thread (k==12 valid only for tl<64: 12*128+64=1600)
    float v[13];
    #pragma unroll
    for (int k = 0; k < 13; ++k) {
        const int nt = k * 128 + tl;
        v[k] = (nt < NT) ? row[nt] : -INFINITY;
    }

    __shared__ float redm[16], reds[16];
    __shared__ float sP[HOPS][NT + 4];     // stride 1604 (mod 32 = 4) -> conflict-free a-column reads

    // row max across 128 threads (2 waves)
    float m = v[0];
    #pragma unroll
    for (int k = 1; k < 13; ++k) m = fmaxf(m, v[k]);
    #pragma unroll
    for (int off = 32; off >= 1; off >>= 1) m = fmaxf(m, __shfl_xor(m, off, 64));
    if (lane == 0) redm[wave] = m;
    __syncthreads();
    m = fmaxf(redm[r * 2], redm[r * 2 + 1]);

    // exp + row sum
    float e[13];
    float s = 0.f;
    #pragma unroll
    for (int k = 0; k < 13; ++k) {
        const int nt = k * 128 + tl;
        e[k] = (nt < NT) ? __expf(v[k] - m) : 0.f;
        s += e[k];
    }
    #pragma unroll
    for (int off = 32; off >= 1; off >>= 1) s += __shfl_xor(s, off, 64);
    if (lane == 0) reds[wave] = s;
    __syncthreads();
    const float inv = 1.0f / (reds[r * 2] + reds[r * 2 + 1]);

    // write softmax row (coalesced 512B per k-slice) + stage P in LDS
    #pragma unroll
    for (int k = 0; k < 13; ++k) {
        const int nt = k * 128 + tl;
        if (nt < NT) {
            const float p = e[k] * inv;
            row[nt] = p;
            sP[r][nt] = p;
        }
    }
    __syncthreads();

    // BW[b][nt] = sum_a P[a][nt] from LDS
    for (int nt = threadIdx.x; nt < NT; nt += 1024) {
        float ssum = 0.f;
        #pragma unroll
        for (int a = 0; a < HOPS; ++a) ssum += sP[a][nt];
        BW[(size_t)b * NT + nt] = ssum;
    }
}

} // namespace

extern "C" void kernel_launch(void* const* d_in, const int* in_sizes, int n_in,
                              void* d_out, int out_size, void* d_ws, size_t ws_size,
                              hipStream_t stream) {
    const float* node  = (const float*)d_in[0];   // [128][50][128] f32
    const float* neigh = (const float*)d_in[1];   // [128][32][50][128] f32
    const int*   nn    = (const int*)d_in[2];     // [128] i32
    const float* W     = (const float*)d_in[3];   // [8][128] f32
    const float* bias  = (const float*)d_in[4];   // [8] f32

    float* out     = (float*)d_out;
    float* BA      = out + Bb * NT;            // after BW (204800)
    float* neigh_r = BA + Bb * HOPS * NT;      // after BA (1638400)

    ga_s1_copy<<<dim3(Bb * CHUNKS), dim3(256), 0, stream>>>(node, neigh, nn, W, bias, BA, neigh_r);
    ga_softmax_bw<<<dim3(Bb), dim3(1024), 0, stream>>>(out);
}